// Round 1
// baseline (271.044 us; speedup 1.0000x reference)
//
#include <hip/hip_runtime.h>
#include <math.h>

namespace {

constexpr int B  = 8;
constexpr int N  = 6;
constexpr int D  = 41;
constexpr int FH = 8;    // 128/16
constexpr int FW = 22;   // 352/16
constexpr int C  = 64;
constexpr int NPTS = B * N * D * FH * FW;   // 346368
constexpr int NX0 = 200, NX1 = 200, NX2 = 1;
constexpr int MAT_STRIDE = 24;              // floats per (b,n): inv_post 9, combine 9, trans 3, post_trans 3

__device__ inline void inv3x3(const float a[9], float r[9]) {
  // adjugate / det
  float c00 = a[4] * a[8] - a[5] * a[7];
  float c01 = a[5] * a[6] - a[3] * a[8];
  float c02 = a[3] * a[7] - a[4] * a[6];
  float det = a[0] * c00 + a[1] * c01 + a[2] * c02;
  float id  = 1.0f / det;
  r[0] = c00 * id;
  r[1] = (a[2] * a[7] - a[1] * a[8]) * id;
  r[2] = (a[1] * a[5] - a[2] * a[4]) * id;
  r[3] = c01 * id;
  r[4] = (a[0] * a[8] - a[2] * a[6]) * id;
  r[5] = (a[2] * a[3] - a[0] * a[5]) * id;
  r[6] = c02 * id;
  r[7] = (a[1] * a[6] - a[0] * a[7]) * id;
  r[8] = (a[0] * a[4] - a[1] * a[3]) * id;
}

// One thread per (b,n): build inv(post_rots+eps I), combine = rots @ inv(intrins+eps I),
// and stash trans / post_trans. 48 sets of 24 floats into d_ws.
__global__ void prep_mats(const float* __restrict__ rots,
                          const float* __restrict__ trans,
                          const float* __restrict__ intrins,
                          const float* __restrict__ post_rots,
                          const float* __restrict__ post_trans,
                          float* __restrict__ mats) {
#pragma clang fp contract(off)
  int i = blockIdx.x * blockDim.x + threadIdx.x;
  if (i >= B * N) return;
  const float eps = 1e-6f;

  float m[9], inv_post[9], ki[9], cm[9];

  // inv(post_rots + eps*I)
  for (int k = 0; k < 9; ++k) m[k] = post_rots[i * 9 + k];
  m[0] += eps; m[4] += eps; m[8] += eps;
  inv3x3(m, inv_post);

  // inv(intrins + eps*I)
  for (int k = 0; k < 9; ++k) m[k] = intrins[i * 9 + k];
  m[0] += eps; m[4] += eps; m[8] += eps;
  inv3x3(m, ki);

  // combine = rots @ ki
  for (int r = 0; r < 3; ++r)
    for (int c = 0; c < 3; ++c)
      cm[r * 3 + c] = rots[i * 9 + r * 3 + 0] * ki[0 * 3 + c]
                    + rots[i * 9 + r * 3 + 1] * ki[1 * 3 + c]
                    + rots[i * 9 + r * 3 + 2] * ki[2 * 3 + c];

  float* o = mats + i * MAT_STRIDE;
  for (int k = 0; k < 9; ++k) o[k]      = inv_post[k];
  for (int k = 0; k < 9; ++k) o[9 + k]  = cm[k];
  for (int k = 0; k < 3; ++k) o[18 + k] = trans[i * 3 + k];
  for (int k = 0; k < 3; ++k) o[21 + k] = post_trans[i * 3 + k];
}

// One 64-lane wave per frustum point. All lanes compute the (identical) geometry,
// wave-uniform cull, then lane c reads x[point, c] (coalesced) and atomicAdds into
// the final (B, C, 1, 200, 200) layout.
__global__ __launch_bounds__(256) void lss_splat(const float* __restrict__ x,
                                                 const float* __restrict__ mats,
                                                 float* __restrict__ out) {
#pragma clang fp contract(off)
  int wid  = blockIdx.x * 4 + (threadIdx.x >> 6);
  if (wid >= NPTS) return;
  int lane = threadIdx.x & 63;

  int t  = wid;
  int w  = t % FW;  t /= FW;
  int h  = t % FH;  t /= FH;
  int dd = t % D;   t /= D;
  int n  = t % N;
  int b  = t / N;

  const float* M = mats + (b * N + n) * MAT_STRIDE;

  // frustum point (image u, image v, depth)
  float u   = (float)w * (351.0f / 21.0f);   // linspace(0, 351, 22)
  float v   = (float)h * (127.0f / 7.0f);    // linspace(0, 127, 8)
  float dep = 4.0f + (float)dd;              // arange(4, 45, 1)

  // subtract post_trans
  float p0 = u - M[21], p1 = v - M[22], p2 = dep - M[23];

  // inv_post @ p
  float q0 = M[0] * p0 + M[1] * p1 + M[2] * p2;
  float q1 = M[3] * p0 + M[4] * p1 + M[5] * p2;
  float q2 = M[6] * p0 + M[7] * p1 + M[8] * p2;

  // safe depth
  float sd;
  if (fabsf(q2) < 1e-6f) {
    float t2 = q2 + 1e-6f;
    float s  = (t2 > 0.0f) ? 1.0f : ((t2 < 0.0f) ? -1.0f : 0.0f);
    sd = 1e-6f * s;
  } else {
    sd = q2;
  }
  float r0 = q0 * sd, r1 = q1 * sd, r2 = sd;

  // combine @ r + trans
  float g0 = (M[9]  * r0 + M[10] * r1 + M[11] * r2) + M[18];
  float g1 = (M[12] * r0 + M[13] * r1 + M[14] * r2) + M[19];
  float g2 = (M[15] * r0 + M[16] * r1 + M[17] * r2) + M[20];

  // voxel indices: (geom - (BX - DX/2)) / DX, truncate
  float gnx = (g0 + 50.0f) / 0.5f;
  float gny = (g1 + 50.0f) / 0.5f;
  float gnz = (g2 + 10.0f) / 20.0f;
  int gx = (int)gnx;
  int gy = (int)gny;
  int gz = (int)gnz;

  if (gx < 0 || gx >= NX0 || gy < 0 || gy >= NX1 || gz < 0 || gz >= NX2) return;

  float val = x[(size_t)wid * C + lane];
  // out[b][c][gz][gx][gy], shape (B, C, NX2, NX0, NX1)
  size_t oidx = (((size_t)(b * C + lane) * NX2 + gz) * NX0 + gx) * NX1 + gy;
  atomicAdd(out + oidx, val);
}

}  // namespace

extern "C" void kernel_launch(void* const* d_in, const int* in_sizes, int n_in,
                              void* d_out, int out_size, void* d_ws, size_t ws_size,
                              hipStream_t stream) {
  const float* x          = (const float*)d_in[0];
  const float* rots       = (const float*)d_in[1];
  const float* trans      = (const float*)d_in[2];
  const float* intrins    = (const float*)d_in[3];
  const float* post_rots  = (const float*)d_in[4];
  const float* post_trans = (const float*)d_in[5];
  float* out  = (float*)d_out;
  float* mats = (float*)d_ws;

  // Output accumulates via atomics -> must be zeroed every call (graph-capturable).
  hipMemsetAsync(d_out, 0, (size_t)out_size * sizeof(float), stream);

  prep_mats<<<1, 64, 0, stream>>>(rots, trans, intrins, post_rots, post_trans, mats);

  int nblocks = (NPTS + 3) / 4;  // 4 waves (points) per 256-thread block
  lss_splat<<<nblocks, 256, 0, stream>>>(x, mats, out);
}

// Round 2
// 74.671 us; speedup vs baseline: 3.6298x; 3.6298x over previous
//
#include <hip/hip_runtime.h>
#include <math.h>

namespace {

constexpr int B  = 8;
constexpr int N  = 6;
constexpr int D  = 41;
constexpr int FH = 8;    // 128/16
constexpr int FW = 22;   // 352/16
constexpr int C  = 64;
constexpr int NPTS = B * N * D * FH * FW;   // 346368 = 1353 * 256
constexpr int NX0 = 200, NX1 = 200, NX2 = 1;
constexpr int NVOX = NX0 * NX1;             // 40000 voxels per batch (gz==0)
constexpr int MAT_STRIDE = 24;
constexpr size_t SCR_ELEMS = (size_t)B * NVOX * C;       // 20,480,000 floats
constexpr size_t SCR_BYTES = SCR_ELEMS * sizeof(float);  // 81,920,000 bytes

__device__ inline void inv3x3(const float a[9], float r[9]) {
  float c00 = a[4] * a[8] - a[5] * a[7];
  float c01 = a[5] * a[6] - a[3] * a[8];
  float c02 = a[3] * a[7] - a[4] * a[6];
  float det = a[0] * c00 + a[1] * c01 + a[2] * c02;
  float id  = 1.0f / det;
  r[0] = c00 * id;
  r[1] = (a[2] * a[7] - a[1] * a[8]) * id;
  r[2] = (a[1] * a[5] - a[2] * a[4]) * id;
  r[3] = c01 * id;
  r[4] = (a[0] * a[8] - a[2] * a[6]) * id;
  r[5] = (a[2] * a[3] - a[0] * a[5]) * id;
  r[6] = c02 * id;
  r[7] = (a[1] * a[6] - a[0] * a[7]) * id;
  r[8] = (a[0] * a[4] - a[1] * a[3]) * id;
}

__global__ void prep_mats(const float* __restrict__ rots,
                          const float* __restrict__ trans,
                          const float* __restrict__ intrins,
                          const float* __restrict__ post_rots,
                          const float* __restrict__ post_trans,
                          float* __restrict__ mats) {
#pragma clang fp contract(off)
  int i = blockIdx.x * blockDim.x + threadIdx.x;
  if (i >= B * N) return;
  const float eps = 1e-6f;

  float m[9], inv_post[9], ki[9], cm[9];

  for (int k = 0; k < 9; ++k) m[k] = post_rots[i * 9 + k];
  m[0] += eps; m[4] += eps; m[8] += eps;
  inv3x3(m, inv_post);

  for (int k = 0; k < 9; ++k) m[k] = intrins[i * 9 + k];
  m[0] += eps; m[4] += eps; m[8] += eps;
  inv3x3(m, ki);

  for (int r = 0; r < 3; ++r)
    for (int c = 0; c < 3; ++c)
      cm[r * 3 + c] = rots[i * 9 + r * 3 + 0] * ki[0 * 3 + c]
                    + rots[i * 9 + r * 3 + 1] * ki[1 * 3 + c]
                    + rots[i * 9 + r * 3 + 2] * ki[2 * 3 + c];

  float* o = mats + i * MAT_STRIDE;
  for (int k = 0; k < 9; ++k) o[k]      = inv_post[k];
  for (int k = 0; k < 9; ++k) o[9 + k]  = cm[k];
  for (int k = 0; k < 3; ++k) o[18 + k] = trans[i * 3 + k];
  for (int k = 0; k < 3; ++k) o[21 + k] = post_trans[i * 3 + k];
}

// Geometry + cull + voxel index, computed per THREAD (not per wave). Shared
// per-point math; kept points are then splatted cooperatively: __ballot the
// kept mask, loop over set bits, all 64 lanes read x[p,64] (256B coalesced)
// and atomicAdd into scratch[(b*NVOX+gx*200+gy)*64 + lane] (256B contiguous).
__device__ inline int point_voxel(int wid, const float* __restrict__ mats) {
#pragma clang fp contract(off)
  int t  = wid;
  int w  = t % FW;  t /= FW;
  int h  = t % FH;  t /= FH;
  int dd = t % D;   t /= D;
  int n  = t % N;
  int b  = t / N;

  const float* M = mats + (b * N + n) * MAT_STRIDE;

  float u   = (float)w * (351.0f / 21.0f);
  float v   = (float)h * (127.0f / 7.0f);
  float dep = 4.0f + (float)dd;

  float p0 = u - M[21], p1 = v - M[22], p2 = dep - M[23];

  float q0 = M[0] * p0 + M[1] * p1 + M[2] * p2;
  float q1 = M[3] * p0 + M[4] * p1 + M[5] * p2;
  float q2 = M[6] * p0 + M[7] * p1 + M[8] * p2;

  float sd;
  if (fabsf(q2) < 1e-6f) {
    float t2 = q2 + 1e-6f;
    float s  = (t2 > 0.0f) ? 1.0f : ((t2 < 0.0f) ? -1.0f : 0.0f);
    sd = 1e-6f * s;
  } else {
    sd = q2;
  }
  float r0 = q0 * sd, r1 = q1 * sd, r2 = sd;

  float g0 = (M[9]  * r0 + M[10] * r1 + M[11] * r2) + M[18];
  float g1 = (M[12] * r0 + M[13] * r1 + M[14] * r2) + M[19];
  float g2 = (M[15] * r0 + M[16] * r1 + M[17] * r2) + M[20];

  float gnx = (g0 + 50.0f) / 0.5f;
  float gny = (g1 + 50.0f) / 0.5f;
  float gnz = (g2 + 10.0f) / 20.0f;
  int gx = (int)gnx;
  int gy = (int)gny;
  int gz = (int)gnz;

  if (gx < 0 || gx >= NX0 || gy < 0 || gy >= NX1 || gz < 0 || gz >= NX2)
    return -1;
  return b * NVOX + gx * NX1 + gy;   // gz == 0
}

__global__ __launch_bounds__(256) void geom_splat(const float* __restrict__ x,
                                                  const float* __restrict__ mats,
                                                  float* __restrict__ scratch) {
  int tid  = blockIdx.x * 256 + threadIdx.x;   // point id; NPTS is a multiple of 256
  int lane = threadIdx.x & 63;
  int base = tid & ~63;                        // wave's first point id

  int voxel = point_voxel(tid, mats);

  unsigned long long m = __ballot(voxel >= 0);
  while (m) {
    int src = __ffsll((long long)m) - 1;
    m &= m - 1;
    int p = base + src;
    int v = __shfl(voxel, src);
    float val = x[(size_t)p * C + lane];
    atomicAdd(scratch + (size_t)v * C + lane, val);
  }
}

// Tiled transpose: scratch (B, NVOX, C) -> out (B, C, NVOX). 64x64 tiles via
// LDS, float4 loads and stores. Writes EVERY output element (no out-memset).
constexpr int VTILES = NVOX / 64;   // 625
__global__ __launch_bounds__(256) void transpose_out(const float* __restrict__ scratch,
                                                     float* __restrict__ out) {
  __shared__ float lds[64][65];
  int bt   = blockIdx.x;
  int b    = bt / VTILES;
  int tile = bt % VTILES;
  int v0   = tile * 64;
  int t    = threadIdx.x;

  const float* src = scratch + ((size_t)b * NVOX + v0) * C;
  int c4 = (t & 15) * 4;
  int r  = t >> 4;            // 0..15
  for (int k = 0; k < 4; ++k) {
    int row = r + k * 16;     // voxel within tile
    float4 vv = *(const float4*)(src + (size_t)row * C + c4);
    lds[row][c4 + 0] = vv.x;
    lds[row][c4 + 1] = vv.y;
    lds[row][c4 + 2] = vv.z;
    lds[row][c4 + 3] = vv.w;
  }
  __syncthreads();

  int vx4 = (t & 15) * 4;     // voxel offset within tile
  int cr  = t >> 4;           // 0..15
  for (int k = 0; k < 4; ++k) {
    int c = cr + k * 16;
    float4 vv;
    vv.x = lds[vx4 + 0][c];
    vv.y = lds[vx4 + 1][c];
    vv.z = lds[vx4 + 2][c];
    vv.w = lds[vx4 + 3][c];
    *(float4*)(out + ((size_t)(b * C + c)) * NVOX + v0 + vx4) = vv;
  }
}

// ---- fallback path (ws too small): round-1 direct-atomic kernel ----
__global__ __launch_bounds__(256) void lss_splat_direct(const float* __restrict__ x,
                                                        const float* __restrict__ mats,
                                                        float* __restrict__ out) {
  int wid  = blockIdx.x * 4 + (threadIdx.x >> 6);
  if (wid >= NPTS) return;
  int lane = threadIdx.x & 63;
  int voxel = point_voxel(wid, mats);
  if (voxel < 0) return;
  int b = voxel / NVOX;
  int v = voxel % NVOX;
  float val = x[(size_t)wid * C + lane];
  size_t oidx = ((size_t)(b * C + lane)) * NVOX + v;
  atomicAdd(out + oidx, val);
}

}  // namespace

extern "C" void kernel_launch(void* const* d_in, const int* in_sizes, int n_in,
                              void* d_out, int out_size, void* d_ws, size_t ws_size,
                              hipStream_t stream) {
  const float* x          = (const float*)d_in[0];
  const float* rots       = (const float*)d_in[1];
  const float* trans      = (const float*)d_in[2];
  const float* intrins    = (const float*)d_in[3];
  const float* post_rots  = (const float*)d_in[4];
  const float* post_trans = (const float*)d_in[5];
  float* out = (float*)d_out;

  // ws layout: [0, SCR_BYTES) scratch accumulator, then 256B-aligned mats.
  const size_t mats_off = (SCR_BYTES + 255) & ~(size_t)255;
  const size_t need     = mats_off + (size_t)B * N * MAT_STRIDE * sizeof(float);

  if (ws_size >= need) {
    float* scratch = (float*)d_ws;
    float* mats    = (float*)((char*)d_ws + mats_off);

    hipMemsetAsync(d_ws, 0, SCR_BYTES, stream);
    prep_mats<<<1, 64, 0, stream>>>(rots, trans, intrins, post_rots, post_trans, mats);
    geom_splat<<<NPTS / 256, 256, 0, stream>>>(x, mats, scratch);
    transpose_out<<<B * VTILES, 256, 0, stream>>>(scratch, out);
  } else {
    // Fallback: direct atomics into out (round-1 path).
    float* mats = (float*)d_ws;  // 4.6 KB
    hipMemsetAsync(d_out, 0, (size_t)out_size * sizeof(float), stream);
    prep_mats<<<1, 64, 0, stream>>>(rots, trans, intrins, post_rots, post_trans, mats);
    lss_splat_direct<<<(NPTS + 3) / 4, 256, 0, stream>>>(x, mats, out);
  }
}

// Round 3
// 57.303 us; speedup vs baseline: 4.7300x; 1.3031x over previous
//
#include <hip/hip_runtime.h>
#include <math.h>

namespace {

constexpr int B  = 8;
constexpr int N  = 6;
constexpr int D  = 41;
constexpr int FH = 8;    // 128/16
constexpr int FW = 22;   // 352/16
constexpr int C  = 64;
constexpr int NPTS = B * N * D * FH * FW;   // 346368 = 1353 * 256
constexpr int NX0 = 200, NX1 = 200, NX2 = 1;
constexpr int NVOX = NX0 * NX1;             // 40000 voxels per batch (gz==0)
constexpr int NVOX_ALL = B * NVOX;          // 320000 (multiple of 256)
constexpr int MAT_STRIDE = 24;
constexpr size_t SCR_ELEMS = (size_t)B * NVOX * C;       // 20,480,000 floats
constexpr size_t SCR_BYTES = SCR_ELEMS * sizeof(float);  // 81,920,000 bytes
constexpr int VTILES = NVOX / 64;           // 625

__device__ inline void inv3x3(const float a[9], float r[9]) {
  float c00 = a[4] * a[8] - a[5] * a[7];
  float c01 = a[5] * a[6] - a[3] * a[8];
  float c02 = a[3] * a[7] - a[4] * a[6];
  float det = a[0] * c00 + a[1] * c01 + a[2] * c02;
  float id  = 1.0f / det;
  r[0] = c00 * id;
  r[1] = (a[2] * a[7] - a[1] * a[8]) * id;
  r[2] = (a[1] * a[5] - a[2] * a[4]) * id;
  r[3] = c01 * id;
  r[4] = (a[0] * a[8] - a[2] * a[6]) * id;
  r[5] = (a[2] * a[3] - a[0] * a[5]) * id;
  r[6] = c02 * id;
  r[7] = (a[1] * a[6] - a[0] * a[7]) * id;
  r[8] = (a[0] * a[4] - a[1] * a[3]) * id;
}

// Build the 24-float matrix pack for camera i into o (inv_post 9, combine 9, trans 3, post_trans 3).
__device__ inline void build_mats(int i,
                                  const float* __restrict__ rots,
                                  const float* __restrict__ trans,
                                  const float* __restrict__ intrins,
                                  const float* __restrict__ post_rots,
                                  const float* __restrict__ post_trans,
                                  float* __restrict__ o) {
#pragma clang fp contract(off)
  const float eps = 1e-6f;
  float m[9], inv_post[9], ki[9];

  for (int k = 0; k < 9; ++k) m[k] = post_rots[i * 9 + k];
  m[0] += eps; m[4] += eps; m[8] += eps;
  inv3x3(m, inv_post);

  for (int k = 0; k < 9; ++k) m[k] = intrins[i * 9 + k];
  m[0] += eps; m[4] += eps; m[8] += eps;
  inv3x3(m, ki);

  for (int k = 0; k < 9; ++k) o[k] = inv_post[k];
  for (int r = 0; r < 3; ++r)
    for (int c = 0; c < 3; ++c)
      o[9 + r * 3 + c] = rots[i * 9 + r * 3 + 0] * ki[0 * 3 + c]
                       + rots[i * 9 + r * 3 + 1] * ki[1 * 3 + c]
                       + rots[i * 9 + r * 3 + 2] * ki[2 * 3 + c];
  for (int k = 0; k < 3; ++k) o[18 + k] = trans[i * 3 + k];
  for (int k = 0; k < 3; ++k) o[21 + k] = post_trans[i * 3 + k];
}

// Geometry + cull + voxel index for point `wid`, reading the matrix pack from `mats`.
__device__ inline int point_voxel(int wid, const float* __restrict__ mats) {
#pragma clang fp contract(off)
  int t  = wid;
  int w  = t % FW;  t /= FW;
  int h  = t % FH;  t /= FH;
  int dd = t % D;   t /= D;
  int n  = t % N;
  int b  = t / N;

  const float* M = mats + (b * N + n) * MAT_STRIDE;

  float u   = (float)w * (351.0f / 21.0f);
  float v   = (float)h * (127.0f / 7.0f);
  float dep = 4.0f + (float)dd;

  float p0 = u - M[21], p1 = v - M[22], p2 = dep - M[23];

  float q0 = M[0] * p0 + M[1] * p1 + M[2] * p2;
  float q1 = M[3] * p0 + M[4] * p1 + M[5] * p2;
  float q2 = M[6] * p0 + M[7] * p1 + M[8] * p2;

  float sd;
  if (fabsf(q2) < 1e-6f) {
    float t2 = q2 + 1e-6f;
    float s  = (t2 > 0.0f) ? 1.0f : ((t2 < 0.0f) ? -1.0f : 0.0f);
    sd = 1e-6f * s;
  } else {
    sd = q2;
  }
  float r0 = q0 * sd, r1 = q1 * sd, r2 = sd;

  float g0 = (M[9]  * r0 + M[10] * r1 + M[11] * r2) + M[18];
  float g1 = (M[12] * r0 + M[13] * r1 + M[14] * r2) + M[19];
  float g2 = (M[15] * r0 + M[16] * r1 + M[17] * r2) + M[20];

  float gnx = (g0 + 50.0f) / 0.5f;
  float gny = (g1 + 50.0f) / 0.5f;
  float gnz = (g2 + 10.0f) / 20.0f;
  int gx = (int)gnx;
  int gy = (int)gny;
  int gz = (int)gnz;

  if (gx < 0 || gx >= NX0 || gy < 0 || gy >= NX1 || gz < 0 || gz >= NX2)
    return -1;
  return b * NVOX + gx * NX1 + gy;   // global voxel id (gz == 0)
}

// Pass 1: per-point voxel id + touched-voxel mask. Mats are built redundantly
// per block into LDS (48 cameras x 24 floats = 4.6 KB) by the first 48 threads.
__global__ __launch_bounds__(256) void mark_kernel(const float* __restrict__ rots,
                                                   const float* __restrict__ trans,
                                                   const float* __restrict__ intrins,
                                                   const float* __restrict__ post_rots,
                                                   const float* __restrict__ post_trans,
                                                   int* __restrict__ vox,
                                                   unsigned char* __restrict__ mask) {
  __shared__ float smats[B * N * MAT_STRIDE];
  int t = threadIdx.x;
  if (t < B * N)
    build_mats(t, rots, trans, intrins, post_rots, post_trans, smats + t * MAT_STRIDE);
  __syncthreads();

  int tid = blockIdx.x * 256 + t;           // NPTS is a multiple of 256
  int v = point_voxel(tid, smats);
  vox[tid] = v;
  if (v >= 0) mask[v] = 1;                  // benign same-value race
}

// Pass 2: zero only the touched voxels' 64-float scratch lines.
__global__ __launch_bounds__(256) void zero_touched(const unsigned char* __restrict__ mask,
                                                    float* __restrict__ scratch) {
  int tid  = blockIdx.x * 256 + threadIdx.x;   // voxel id; NVOX_ALL multiple of 256
  int lane = threadIdx.x & 63;
  int base = tid & ~63;

  bool touched = mask[tid] != 0;
  unsigned long long m = __ballot(touched);
  while (m) {
    int src = __ffsll((long long)m) - 1;
    m &= m - 1;
    int v = base + src;
    scratch[(size_t)v * C + lane] = 0.0f;
  }
}

// Pass 3: splat kept points into scratch (voxel-contiguous atomics).
__global__ __launch_bounds__(256) void splat_kernel(const float* __restrict__ x,
                                                    const int* __restrict__ vox,
                                                    float* __restrict__ scratch) {
  int tid  = blockIdx.x * 256 + threadIdx.x;
  int lane = threadIdx.x & 63;
  int base = tid & ~63;

  int v = vox[tid];
  unsigned long long m = __ballot(v >= 0);
  while (m) {
    int src = __ffsll((long long)m) - 1;
    m &= m - 1;
    int p  = base + src;
    int vv = __shfl(v, src);
    float val = x[(size_t)p * C + lane];
    atomicAdd(scratch + (size_t)vv * C + lane, val);
  }
}

// Pass 4: (B, NVOX, C) -> (B, C, NVOX) transpose with mask. Untouched rows are
// zeros without reading scratch; fully-untouched tiles stream zeros directly.
__global__ __launch_bounds__(256) void transpose_out(const float* __restrict__ scratch,
                                                     const unsigned char* __restrict__ mask,
                                                     float* __restrict__ out) {
  __shared__ float lds[64][65];
  __shared__ int any_touched;
  int bt   = blockIdx.x;
  int b    = bt / VTILES;
  int tile = bt % VTILES;
  int v0   = tile * 64;
  int t    = threadIdx.x;

  const unsigned char* mrow = mask + (size_t)b * NVOX + v0;

  if (t == 0) any_touched = 0;
  __syncthreads();
  if (t < 64 && mrow[t]) any_touched = 1;   // benign same-value race
  __syncthreads();

  int vx4 = (t & 15) * 4;   // voxel offset for the write phase
  int cr  = t >> 4;

  if (!any_touched) {
    float4 z = make_float4(0.f, 0.f, 0.f, 0.f);
    for (int k = 0; k < 4; ++k) {
      int c = cr + k * 16;
      *(float4*)(out + ((size_t)(b * C + c)) * NVOX + v0 + vx4) = z;
    }
    return;
  }

  int c4 = (t & 15) * 4;
  int r  = t >> 4;
  for (int k = 0; k < 4; ++k) {
    int row = r + k * 16;
    float4 vv = make_float4(0.f, 0.f, 0.f, 0.f);
    if (mrow[row])
      vv = *(const float4*)(scratch + ((size_t)(b * NVOX + v0 + row)) * C + c4);
    lds[row][c4 + 0] = vv.x;
    lds[row][c4 + 1] = vv.y;
    lds[row][c4 + 2] = vv.z;
    lds[row][c4 + 3] = vv.w;
  }
  __syncthreads();

  for (int k = 0; k < 4; ++k) {
    int c = cr + k * 16;
    float4 vv;
    vv.x = lds[vx4 + 0][c];
    vv.y = lds[vx4 + 1][c];
    vv.z = lds[vx4 + 2][c];
    vv.w = lds[vx4 + 3][c];
    *(float4*)(out + ((size_t)(b * C + c)) * NVOX + v0 + vx4) = vv;
  }
}

// ---- fallback path (ws too small): direct atomics into out ----
__global__ void prep_mats(const float* __restrict__ rots,
                          const float* __restrict__ trans,
                          const float* __restrict__ intrins,
                          const float* __restrict__ post_rots,
                          const float* __restrict__ post_trans,
                          float* __restrict__ mats) {
  int i = blockIdx.x * blockDim.x + threadIdx.x;
  if (i >= B * N) return;
  build_mats(i, rots, trans, intrins, post_rots, post_trans, mats + i * MAT_STRIDE);
}

__global__ __launch_bounds__(256) void lss_splat_direct(const float* __restrict__ x,
                                                        const float* __restrict__ mats,
                                                        float* __restrict__ out) {
  int wid  = blockIdx.x * 4 + (threadIdx.x >> 6);
  if (wid >= NPTS) return;
  int lane = threadIdx.x & 63;
  int voxel = point_voxel(wid, mats);
  if (voxel < 0) return;
  int b = voxel / NVOX;
  int v = voxel % NVOX;
  float val = x[(size_t)wid * C + lane];
  size_t oidx = ((size_t)(b * C + lane)) * NVOX + v;
  atomicAdd(out + oidx, val);
}

}  // namespace

extern "C" void kernel_launch(void* const* d_in, const int* in_sizes, int n_in,
                              void* d_out, int out_size, void* d_ws, size_t ws_size,
                              hipStream_t stream) {
  const float* x          = (const float*)d_in[0];
  const float* rots       = (const float*)d_in[1];
  const float* trans      = (const float*)d_in[2];
  const float* intrins    = (const float*)d_in[3];
  const float* post_rots  = (const float*)d_in[4];
  const float* post_trans = (const float*)d_in[5];
  float* out = (float*)d_out;

  // ws layout: scratch (82 MB) | mask (320 KB) | vox (1.39 MB)
  const size_t mask_off = (SCR_BYTES + 255) & ~(size_t)255;
  const size_t vox_off  = (mask_off + (size_t)NVOX_ALL + 255) & ~(size_t)255;
  const size_t need     = vox_off + (size_t)NPTS * sizeof(int);

  if (ws_size >= need) {
    float*         scratch = (float*)d_ws;
    unsigned char* mask    = (unsigned char*)d_ws + mask_off;
    int*           vox     = (int*)((char*)d_ws + vox_off);

    hipMemsetAsync(mask, 0, (size_t)NVOX_ALL, stream);
    mark_kernel<<<NPTS / 256, 256, 0, stream>>>(rots, trans, intrins, post_rots,
                                                post_trans, vox, mask);
    zero_touched<<<NVOX_ALL / 256, 256, 0, stream>>>(mask, scratch);
    splat_kernel<<<NPTS / 256, 256, 0, stream>>>(x, vox, scratch);
    transpose_out<<<B * VTILES, 256, 0, stream>>>(scratch, mask, out);
  } else {
    // Fallback: direct atomics into out.
    float* mats = (float*)d_ws;  // 4.6 KB
    hipMemsetAsync(d_out, 0, (size_t)out_size * sizeof(float), stream);
    prep_mats<<<1, 64, 0, stream>>>(rots, trans, intrins, post_rots, post_trans, mats);
    lss_splat_direct<<<(NPTS + 3) / 4, 256, 0, stream>>>(x, mats, out);
  }
}